// Round 3
// baseline (282.246 us; speedup 1.0000x reference)
//
#include <hip/hip_runtime.h>
#include <hip/hip_bf16.h>
#include <cstdint>

#define BATCH 4
#define S_LEN 2048
#define D_DIM 1024

typedef __attribute__((ext_vector_type(4))) float f32x4_t;
typedef __attribute__((ext_vector_type(8))) __bf16 bf16x8_t;

__device__ __forceinline__ ushort f32_to_bf16(float f) {
    uint32_t u = __float_as_uint(f);
    uint32_t r = (u + 0x7FFFu + ((u >> 16) & 1u)) >> 16;
    return (ushort)r;
}

// ---------------- fp32 -> bf16 convert, 3 tensors in one launch ----------------
__global__ __launch_bounds__(256)
void cvt3_kernel(const float* __restrict__ a, const float* __restrict__ b,
                 const float* __restrict__ c, ushort* __restrict__ out, int n4) {
    int z = blockIdx.y;
    const float* src = (z == 0) ? a : ((z == 1) ? b : c);
    ushort* dst = out + (size_t)z * n4 * 4;
    int idx = blockIdx.x * blockDim.x + threadIdx.x;
    int stride = gridDim.x * blockDim.x;
    const float4* in4 = (const float4*)src;
    ushort4* out4 = (ushort4*)dst;
    for (int i = idx; i < n4; i += stride) {
        float4 v = in4[i];
        ushort4 o;
        o.x = f32_to_bf16(v.x);
        o.y = f32_to_bf16(v.y);
        o.z = f32_to_bf16(v.z);
        o.w = f32_to_bf16(v.w);
        out4[i] = o;
    }
}

// ---------------- fp32 [rows][cols] -> bf16 [cols][rows] ----------------
__global__ __launch_bounds__(256)
void transpose_cvt_kernel(const float* __restrict__ in, ushort* __restrict__ out,
                          int rows, int cols) {
    __shared__ ushort tile[64][66];
    int r0 = blockIdx.y * 64, c0 = blockIdx.x * 64;
    int t = threadIdx.x;
    int cr = t & 63;
    int cc = t >> 6;
    #pragma unroll
    for (int i = 0; i < 16; ++i) {
        int r = cc * 16 + i;
        tile[r][cr] = f32_to_bf16(in[(size_t)(r0 + r) * cols + (c0 + cr)]);
    }
    __syncthreads();
    #pragma unroll
    for (int i = 0; i < 16; ++i) {
        int c = cc * 16 + i;
        out[(size_t)(c0 + c) * rows + (r0 + cr)] = tile[cr][c];
    }
}

// ---------------- bf16 strided [rows][cols] -> bf16 [cols][rows], batched ----------------
__global__ __launch_bounds__(256)
void transpose_bf16_kernel(const ushort* __restrict__ in, ushort* __restrict__ out,
                           int rows, int cols, int lda, long strideA, long strideB) {
    __shared__ ushort tile[64][66];
    const ushort* src = in + (size_t)blockIdx.z * strideA;
    ushort* dst = out + (size_t)blockIdx.z * strideB;
    int r0 = blockIdx.y * 64, c0 = blockIdx.x * 64;
    int t = threadIdx.x;
    int cr = t & 63;
    int cc = t >> 6;
    #pragma unroll
    for (int i = 0; i < 16; ++i) {
        int r = cc * 16 + i;
        tile[r][cr] = src[(size_t)(r0 + r) * lda + (c0 + cr)];
    }
    __syncthreads();
    #pragma unroll
    for (int i = 0; i < 16; ++i) {
        int c = cc * 16 + i;
        dst[(size_t)(c0 + c) * rows + (r0 + cr)] = tile[cr][c];
    }
}

// ---------------- bias concat ----------------
__global__ __launch_bounds__(256)
void bias_concat_kernel(const float* __restrict__ bq, const float* __restrict__ bk,
                        const float* __restrict__ bv, float* __restrict__ out) {
    int i = blockIdx.x * blockDim.x + threadIdx.x;
    if (i < D_DIM) out[i] = bq[i];
    else if (i < 2 * D_DIM) out[i] = bk[i - D_DIM];
    else if (i < 3 * D_DIM) out[i] = bv[i - 2 * D_DIM];
}

// =====================================================================
// bf16 GEMM  C = A(MxK) * Bt(NxK)^T
// BM=256 BN=128 BK=64, 512 threads (8 waves 2x4), triple-buffered LDS,
// counted-vmcnt pipeline (T3+T4), XOR-swizzled LDS (T2), setprio (T5).
// =====================================================================
enum { MODE_PROJ = 0, MODE_LOGITS = 1, MODE_OUT = 2 };

#define BM 256
#define BN 128
#define BK 64
#define NSLOT 3

template<int MODE>
__global__ __launch_bounds__(512, 1)
void gemm3_kernel(const ushort* __restrict__ A, const ushort* __restrict__ Bt,
                  const float* __restrict__ bias, void* __restrict__ Cout,
                  int K, int lda, int ldb, int ldc,
                  long strideA, long strideB, long strideC, float scale) {
    int bc = blockIdx.x, br = blockIdx.y, bz = blockIdx.z;
    if (MODE == MODE_LOGITS && bc >= 2 * (br + 1)) return;  // fully-masked causal block

    __shared__ ushort As[NSLOT][BM * BK];   // 3 x 32 KB
    __shared__ ushort Bs[NSLOT][BN * BK];   // 3 x 16 KB

    const ushort* Ab = (MODE == MODE_PROJ) ? A + (size_t)(bc >> 3) * strideA
                                           : A + (size_t)bz * strideA;
    const ushort* Bb = Bt + (size_t)bz * strideB;

    int brow = br * BM, bcol = bc * BN;
    int t = threadIdx.x;
    int lane = t & 63;
    int wid = t >> 6;
    int wr = wid >> 2, wc = wid & 3;   // 2 x 4 wave grid; wave tile 128x32

    int nkt = K / BK;
    if (MODE == MODE_OUT) nkt = min(nkt, (brow + BM) / BK);  // causal K-limit

    // ---- staging: linear LDS dest + inverse-swizzled global source (rule #21)
    // tile rows are 128 B; swizzle: byte ^= (row&7)<<4  (involution)
    auto stageA = [&](int kt, int slot, int j) {
        int o = (j * 512 + t) * 16;                 // linear byte offset in 32KB tile
        int row = o >> 7;
        int col = (o & 127) ^ ((row & 7) << 4);
        const ushort* src = Ab + (size_t)(brow + row) * lda + kt * BK + (col >> 1);
        __builtin_amdgcn_global_load_lds(
            (const __attribute__((address_space(1))) uint32_t*)src,
            (__attribute__((address_space(3))) uint32_t*)&As[slot][o >> 1],
            16, 0, 0);
    };
    auto stageB = [&](int kt, int slot, int j) {
        int o = (j * 512 + t) * 16;                 // linear byte offset in 16KB tile
        int row = o >> 7;
        int col = (o & 127) ^ ((row & 7) << 4);
        const ushort* src = Bb + (size_t)(bcol + row) * ldb + kt * BK + (col >> 1);
        __builtin_amdgcn_global_load_lds(
            (const __attribute__((address_space(1))) uint32_t*)src,
            (__attribute__((address_space(3))) uint32_t*)&Bs[slot][o >> 1],
            16, 0, 0);
    };

    f32x4_t acc[8][2];
    #pragma unroll
    for (int m = 0; m < 8; ++m)
        #pragma unroll
        for (int n = 0; n < 2; ++n)
            acc[m][n] = (f32x4_t){0.f, 0.f, 0.f, 0.f};

    bf16x8_t af[4][2], bf[2][2];

    auto readA = [&](int slot, int mh) {
        #pragma unroll
        for (int m = 0; m < 4; ++m) {
            int ra = wr * 128 + mh * 64 + m * 16 + (lane & 15);
            int sw = (ra & 7) << 4;
            #pragma unroll
            for (int ks = 0; ks < 2; ++ks) {
                int cb = ks * 64 + ((lane >> 4) * 16);
                af[m][ks] = *(const bf16x8_t*)((const char*)&As[slot][0] + ra * 128 + (cb ^ sw));
            }
        }
    };
    auto readB = [&](int slot) {
        #pragma unroll
        for (int n = 0; n < 2; ++n) {
            int rb = wc * 32 + n * 16 + (lane & 15);
            int sw = (rb & 7) << 4;
            #pragma unroll
            for (int ks = 0; ks < 2; ++ks) {
                int cb = ks * 64 + ((lane >> 4) * 16);
                bf[n][ks] = *(const bf16x8_t*)((const char*)&Bs[slot][0] + rb * 128 + (cb ^ sw));
            }
        }
    };

    // ---- prologue: stage kt0 -> slot0, kt1 -> slot1 (6 loads each) ----
    #pragma unroll
    for (int j = 0; j < 4; ++j) stageA(0, 0, j);
    stageB(0, 0, 0); stageB(0, 0, 1);
    #pragma unroll
    for (int j = 0; j < 4; ++j) stageA(1, 1, j);
    stageB(1, 1, 0); stageB(1, 1, 1);
    asm volatile("s_waitcnt vmcnt(6)" ::: "memory");   // kt0's 6 loads landed
    __builtin_amdgcn_sched_barrier(0);
    __builtin_amdgcn_s_barrier();

    int slot = 0;
    for (int kt = 0; kt < nkt; ++kt) {
        int sslot = slot + 2; if (sslot >= NSLOT) sslot -= NSLOT;
        bool dostage = (kt + 2 < nkt);

        // ---- phase 0: quadrant mh=0 ----
        if (dostage) { stageA(kt + 2, sslot, 0); stageA(kt + 2, sslot, 1); stageB(kt + 2, sslot, 0); }
        readB(slot);
        readA(slot, 0);
        asm volatile("s_waitcnt lgkmcnt(0)" ::: "memory");
        __builtin_amdgcn_sched_barrier(0);
        __builtin_amdgcn_s_setprio(1);
        #pragma unroll
        for (int m = 0; m < 4; ++m)
            #pragma unroll
            for (int n = 0; n < 2; ++n)
                #pragma unroll
                for (int ks = 0; ks < 2; ++ks)
                    acc[m][n] = __builtin_amdgcn_mfma_f32_16x16x32_bf16(
                        af[m][ks], bf[n][ks], acc[m][n], 0, 0, 0);
        __builtin_amdgcn_s_setprio(0);
        __builtin_amdgcn_s_barrier();

        // ---- phase 1: quadrant mh=1 ----
        if (dostage) { stageA(kt + 2, sslot, 2); stageA(kt + 2, sslot, 3); stageB(kt + 2, sslot, 1); }
        readA(slot, 1);
        asm volatile("s_waitcnt lgkmcnt(0)" ::: "memory");
        __builtin_amdgcn_sched_barrier(0);
        __builtin_amdgcn_s_setprio(1);
        #pragma unroll
        for (int m = 0; m < 4; ++m)
            #pragma unroll
            for (int n = 0; n < 2; ++n)
                #pragma unroll
                for (int ks = 0; ks < 2; ++ks)
                    acc[4 + m][n] = __builtin_amdgcn_mfma_f32_16x16x32_bf16(
                        af[m][ks], bf[n][ks], acc[4 + m][n], 0, 0, 0);
        __builtin_amdgcn_s_setprio(0);
        // counted vmcnt: kt+1's 6 loads must be landed before next iteration;
        // 6 loads (kt+2's) were issued after them -> vmcnt(6). Tail: drain.
        if (dostage) { asm volatile("s_waitcnt vmcnt(6)" ::: "memory"); }
        else         { asm volatile("s_waitcnt vmcnt(0)" ::: "memory"); }
        __builtin_amdgcn_sched_barrier(0);
        __builtin_amdgcn_s_barrier();

        slot += 1; if (slot >= NSLOT) slot -= NSLOT;
    }

    // ---- epilogue: C/D layout col = lane&15, row = (lane>>4)*4 + j ----
    int crow0 = brow + wr * 128 + ((lane >> 4) * 4);
    int ccol0 = bcol + wc * 32 + (lane & 15);
    if (MODE == MODE_PROJ) {
        ushort* C = (ushort*)Cout;
        #pragma unroll
        for (int m = 0; m < 8; ++m) {
            #pragma unroll
            for (int n = 0; n < 2; ++n) {
                int col = ccol0 + n * 16;
                float bv = bias[col];
                #pragma unroll
                for (int j = 0; j < 4; ++j) {
                    int rowg = crow0 + m * 16 + j;
                    C[(size_t)rowg * ldc + col] = f32_to_bf16(acc[m][n][j] + bv);
                }
            }
        }
    } else {
        float* C = (float*)Cout + (size_t)bz * strideC;
        #pragma unroll
        for (int m = 0; m < 8; ++m)
            #pragma unroll
            for (int n = 0; n < 2; ++n) {
                int col = ccol0 + n * 16;
                #pragma unroll
                for (int j = 0; j < 4; ++j) {
                    int rowg = crow0 + m * 16 + j;
                    C[(size_t)rowg * ldc + col] = acc[m][n][j] * scale;
                }
            }
    }
}

// ---------------- causal row softmax (in-place fp32, plus bf16 copy) ----------------
__global__ __launch_bounds__(256)
void softmax_causal_kernel(float* __restrict__ attn, ushort* __restrict__ attn_bf) {
    int rowid = blockIdx.x;            // 0 .. B*S-1
    int i = rowid & (S_LEN - 1);       // query index within sequence
    float* lrow = attn + (size_t)rowid * S_LEN;
    ushort* brw = attn_bf + (size_t)rowid * S_LEN;
    int t = threadIdx.x;
    int nvalid = i + 1;

    float vals[8];
    float lmax = -1e30f;
    #pragma unroll
    for (int it = 0; it < 8; ++it) {
        int j = it * 256 + t;
        float v = (j < nvalid) ? lrow[j] : -1e30f;
        vals[it] = v;
        lmax = fmaxf(lmax, v);
    }
    #pragma unroll
    for (int off = 32; off > 0; off >>= 1)
        lmax = fmaxf(lmax, __shfl_xor(lmax, off));

    __shared__ float redm[4];
    __shared__ float reds[4];
    int wave = t >> 6, lane = t & 63;
    if (lane == 0) redm[wave] = lmax;
    __syncthreads();
    float m = fmaxf(fmaxf(redm[0], redm[1]), fmaxf(redm[2], redm[3]));

    float lsum = 0.f;
    #pragma unroll
    for (int it = 0; it < 8; ++it) {
        int j = it * 256 + t;
        float e = (j < nvalid) ? __expf(vals[it] - m) : 0.f;
        vals[it] = e;
        lsum += e;
    }
    #pragma unroll
    for (int off = 32; off > 0; off >>= 1)
        lsum += __shfl_xor(lsum, off);
    if (lane == 0) reds[wave] = lsum;
    __syncthreads();
    float denom = reds[0] + reds[1] + reds[2] + reds[3];
    float inv = 1.f / denom;

    #pragma unroll
    for (int it = 0; it < 8; ++it) {
        int j = it * 256 + t;
        float p = vals[it] * inv;
        lrow[j] = p;
        brw[j] = f32_to_bf16(p);
    }
}

extern "C" void kernel_launch(void* const* d_in, const int* in_sizes, int n_in,
                              void* d_out, int out_size, void* d_ws, size_t ws_size,
                              hipStream_t stream) {
    const float* v  = (const float*)d_in[0];
    const float* k  = (const float*)d_in[1];
    const float* q  = (const float*)d_in[2];
    // d_in[3] = mask, unused (causality applied by index)
    const float* Wq = (const float*)d_in[4];
    const float* bq = (const float*)d_in[5];
    const float* Wk = (const float*)d_in[6];
    const float* bk = (const float*)d_in[7];
    const float* Wv = (const float*)d_in[8];
    const float* bv = (const float*)d_in[9];

    float* out  = (float*)d_out;                                        // [B,S,D]
    float* attn = (float*)d_out + (size_t)BATCH * S_LEN * D_DIM;        // [B,S,S]

    char* ws = (char*)d_ws;
    const size_t NTOK = (size_t)BATCH * S_LEN;                // 8192
    const size_t XSZ  = NTOK * D_DIM * sizeof(ushort);        // 16 MiB
    ushort* xqkv  = (ushort*)(ws);                            // [3][8192][1024] bf16, 48 MiB
    ushort* qkvp  = (ushort*)(ws + 3 * XSZ);                  // [8192][3072] bf16, 48 MiB
    ushort* WT    = (ushort*)(ws + 6 * XSZ);                  // [3072][1024] bf16, 6 MiB
    float*  bias3 = (float*)(ws + 6 * XSZ + 3 * (size_t)D_DIM * D_DIM * sizeof(ushort));
    // aliases over xqkv (dead after projection GEMM):
    ushort* vpT     = (ushort*)(ws);            // [B][1024][2048] bf16, 16 MiB
    ushort* attn_bf = (ushort*)(ws + XSZ);      // [B][2048][2048] bf16, 32 MiB

    const int n4 = (int)(NTOK * D_DIM / 4);
    cvt3_kernel<<<dim3(1024, 3), dim3(256), 0, stream>>>(q, k, v, xqkv, n4);

    transpose_cvt_kernel<<<dim3(16, 16), dim3(256), 0, stream>>>(Wq, WT, D_DIM, D_DIM);
    transpose_cvt_kernel<<<dim3(16, 16), dim3(256), 0, stream>>>(Wk, WT + (size_t)D_DIM * D_DIM, D_DIM, D_DIM);
    transpose_cvt_kernel<<<dim3(16, 16), dim3(256), 0, stream>>>(Wv, WT + 2 * (size_t)D_DIM * D_DIM, D_DIM, D_DIM);
    bias_concat_kernel<<<dim3(12), dim3(256), 0, stream>>>(bq, bk, bv, bias3);

    // merged projections: M = 8192, N = 3072 (q|k|v), K = 1024
    dim3 pgrid(3 * D_DIM / BN, (int)(NTOK / BM), 1);
    gemm3_kernel<MODE_PROJ><<<pgrid, dim3(512), 0, stream>>>(
        xqkv, WT, bias3, qkvp, D_DIM, D_DIM, D_DIM, 3 * D_DIM,
        (long)NTOK * D_DIM, 0, 0, 1.f);

    // vp (cols 2048..3071 of qkvp) -> vpT [B,D,S]
    transpose_bf16_kernel<<<dim3(D_DIM / 64, S_LEN / 64, BATCH), dim3(256), 0, stream>>>(
        qkvp + 2 * D_DIM, vpT, S_LEN, D_DIM, 3 * D_DIM,
        (long)S_LEN * 3 * D_DIM, (long)D_DIM * S_LEN);

    // logits = qp @ kp^T / 32, causal blocks only, fp32 into attn region of d_out
    dim3 lgrid(S_LEN / BN, S_LEN / BM, BATCH);
    gemm3_kernel<MODE_LOGITS><<<lgrid, dim3(512), 0, stream>>>(
        qkvp, qkvp + D_DIM, nullptr, attn, D_DIM, 3 * D_DIM, 3 * D_DIM, S_LEN,
        (long)S_LEN * 3 * D_DIM, (long)S_LEN * 3 * D_DIM, (long)S_LEN * S_LEN, 0.03125f);

    // softmax rows (fp32 in-place in d_out; bf16 copy for PV)
    softmax_causal_kernel<<<dim3((int)NTOK), dim3(256), 0, stream>>>(attn, attn_bf);

    // out = attn_bf @ vp (via vpT), causal K-limit
    dim3 ogrid(D_DIM / BN, S_LEN / BM, BATCH);
    gemm3_kernel<MODE_OUT><<<ogrid, dim3(512), 0, stream>>>(
        attn_bf, vpT, nullptr, out, S_LEN, S_LEN, S_LEN, D_DIM,
        (long)S_LEN * S_LEN, (long)D_DIM * S_LEN, (long)S_LEN * D_DIM, 1.f);
}

// Round 4
// 242.603 us; speedup vs baseline: 1.1634x; 1.1634x over previous
//
#include <hip/hip_runtime.h>
#include <hip/hip_bf16.h>
#include <cstdint>

#define BATCH 4
#define S_LEN 2048
#define D_DIM 1024

typedef __attribute__((ext_vector_type(4))) float f32x4_t;
typedef __attribute__((ext_vector_type(8))) __bf16 bf16x8_t;

__device__ __forceinline__ ushort f32_to_bf16(float f) {
    uint32_t u = __float_as_uint(f);
    uint32_t r = (u + 0x7FFFu + ((u >> 16) & 1u)) >> 16;
    return (ushort)r;
}

// ---------------- fp32 -> bf16 convert, 3 tensors in one launch ----------------
__global__ __launch_bounds__(256)
void cvt3_kernel(const float* __restrict__ a, const float* __restrict__ b,
                 const float* __restrict__ c, ushort* __restrict__ out, int n4) {
    int z = blockIdx.y;
    const float* src = (z == 0) ? a : ((z == 1) ? b : c);
    ushort* dst = out + (size_t)z * n4 * 4;
    int idx = blockIdx.x * blockDim.x + threadIdx.x;
    int stride = gridDim.x * blockDim.x;
    const float4* in4 = (const float4*)src;
    ushort4* out4 = (ushort4*)dst;
    for (int i = idx; i < n4; i += stride) {
        float4 v = in4[i];
        ushort4 o;
        o.x = f32_to_bf16(v.x);
        o.y = f32_to_bf16(v.y);
        o.z = f32_to_bf16(v.z);
        o.w = f32_to_bf16(v.w);
        out4[i] = o;
    }
}

// ---------------- fp32 [rows][cols] -> bf16 [cols][rows] ----------------
__global__ __launch_bounds__(256)
void transpose_cvt_kernel(const float* __restrict__ in, ushort* __restrict__ out,
                          int rows, int cols) {
    __shared__ ushort tile[64][66];
    int r0 = blockIdx.y * 64, c0 = blockIdx.x * 64;
    int t = threadIdx.x;
    int cr = t & 63;
    int cc = t >> 6;
    #pragma unroll
    for (int i = 0; i < 16; ++i) {
        int r = cc * 16 + i;
        tile[r][cr] = f32_to_bf16(in[(size_t)(r0 + r) * cols + (c0 + cr)]);
    }
    __syncthreads();
    #pragma unroll
    for (int i = 0; i < 16; ++i) {
        int c = cc * 16 + i;
        out[(size_t)(c0 + c) * rows + (r0 + cr)] = tile[cr][c];
    }
}

// ---------------- bf16 strided [rows][cols] -> bf16 [cols][rows], batched ----------------
__global__ __launch_bounds__(256)
void transpose_bf16_kernel(const ushort* __restrict__ in, ushort* __restrict__ out,
                           int rows, int cols, int lda, long strideA, long strideB) {
    __shared__ ushort tile[64][66];
    const ushort* src = in + (size_t)blockIdx.z * strideA;
    ushort* dst = out + (size_t)blockIdx.z * strideB;
    int r0 = blockIdx.y * 64, c0 = blockIdx.x * 64;
    int t = threadIdx.x;
    int cr = t & 63;
    int cc = t >> 6;
    #pragma unroll
    for (int i = 0; i < 16; ++i) {
        int r = cc * 16 + i;
        tile[r][cr] = src[(size_t)(r0 + r) * lda + (c0 + cr)];
    }
    __syncthreads();
    #pragma unroll
    for (int i = 0; i < 16; ++i) {
        int c = cc * 16 + i;
        dst[(size_t)(c0 + c) * rows + (r0 + cr)] = tile[cr][c];
    }
}

// ---------------- bias concat ----------------
__global__ __launch_bounds__(256)
void bias_concat_kernel(const float* __restrict__ bq, const float* __restrict__ bk,
                        const float* __restrict__ bv, float* __restrict__ out) {
    int i = blockIdx.x * blockDim.x + threadIdx.x;
    if (i < D_DIM) out[i] = bq[i];
    else if (i < 2 * D_DIM) out[i] = bk[i - D_DIM];
    else if (i < 3 * D_DIM) out[i] = bv[i - 2 * D_DIM];
}

// =====================================================================
// 8-phase m201-style GEMM schedule (T1+T2+T3+T4+T5)
// =====================================================================
enum { MODE_PROJ = 0, MODE_LOGITS = 1, MODE_OUT = 2 };

#define PRE_BAR() do { __builtin_amdgcn_sched_barrier(0); __builtin_amdgcn_s_barrier(); \
    asm volatile("s_waitcnt lgkmcnt(0)" ::: "memory"); __builtin_amdgcn_sched_barrier(0); } while (0)
#define POST_BAR() do { __builtin_amdgcn_sched_barrier(0); __builtin_amdgcn_s_barrier(); } while (0)
#define GATE(N) do { asm volatile("s_waitcnt vmcnt(" #N ")" ::: "memory"); \
    __builtin_amdgcn_sched_barrier(0); } while (0)

// bijective XCD swizzle over (x,y) grid, x fastest
__device__ __forceinline__ void xcd_swizzle(int& bc, int& br) {
    int gx = gridDim.x;
    int nwg = gx * gridDim.y;
    int orig = blockIdx.y * gx + blockIdx.x;
    int xcd = orig & 7, idx = orig >> 3;
    int q8 = nwg >> 3, r8 = nwg & 7;
    int wgid = (xcd < r8 ? xcd * (q8 + 1) : r8 * (q8 + 1) + (xcd - r8) * q8) + idx;
    bc = wgid % gx;
    br = wgid / gx;
}

// ---------------------------------------------------------------------
// 256x256 tile, BK=64, 512 thr (8 waves 2x4), wave tile 128x64. PROJ only.
// LDS: A 2x32KB + B 2x32KB = 128 KB.
// ---------------------------------------------------------------------
__global__ __launch_bounds__(512, 2)
void gemm_proj_kernel(const ushort* __restrict__ A, const ushort* __restrict__ Bt,
                      const float* __restrict__ bias, ushort* __restrict__ Cout,
                      int K, int lda, int ldb, int ldc, long strideA) {
    __shared__ ushort As[2][256 * 64];
    __shared__ ushort Bs[2][256 * 64];
    int bc, br;
    xcd_swizzle(bc, br);
    const ushort* Ab = A + (size_t)(bc >> 2) * strideA;   // q/k/v select: 4 blocks of 256 cols each
    const ushort* Bb = Bt;
    int brow = br * 256, bcol = bc * 256;
    int t = threadIdx.x, lane = t & 63, wid = t >> 6;
    int wr = wid >> 2, wc = wid & 3;
    int nkt = K / 64, niter = nkt >> 1;

    auto stageA = [&](int tk, int half) {
        ushort* dst = &As[tk & 1][0];
        #pragma unroll
        for (int j = 0; j < 2; ++j) {
            int o = half * 16384 + (j * 512 + t) * 16;
            int row = o >> 7;
            int col = (o & 127) ^ ((row & 7) << 4);
            const ushort* src = Ab + (size_t)(brow + row) * lda + tk * 64 + (col >> 1);
            __builtin_amdgcn_global_load_lds(
                (const __attribute__((address_space(1))) uint32_t*)src,
                (__attribute__((address_space(3))) uint32_t*)(dst + (o >> 1)), 16, 0, 0);
        }
    };
    auto stageB = [&](int tk, int half) {
        ushort* dst = &Bs[tk & 1][0];
        #pragma unroll
        for (int j = 0; j < 2; ++j) {
            int o = half * 16384 + (j * 512 + t) * 16;
            int row = o >> 7;
            int col = (o & 127) ^ ((row & 7) << 4);
            const ushort* src = Bb + (size_t)(bcol + row) * ldb + tk * 64 + (col >> 1);
            __builtin_amdgcn_global_load_lds(
                (const __attribute__((address_space(1))) uint32_t*)src,
                (__attribute__((address_space(3))) uint32_t*)(dst + (o >> 1)), 16, 0, 0);
        }
    };

    f32x4_t acc[8][4];
    #pragma unroll
    for (int m = 0; m < 8; ++m)
        #pragma unroll
        for (int n = 0; n < 4; ++n)
            acc[m][n] = (f32x4_t){0.f, 0.f, 0.f, 0.f};

    bf16x8_t afl[4][2], afh[4][2], bfr[4][2];

    auto readAhalf = [&](int tk, int mh, bf16x8_t (&dst)[4][2]) {
        const char* base = (const char*)&As[tk & 1][0];
        #pragma unroll
        for (int m = 0; m < 4; ++m) {
            int ra = wr * 128 + mh * 64 + m * 16 + (lane & 15);
            int sw = (ra & 7) << 4;
            #pragma unroll
            for (int ks = 0; ks < 2; ++ks) {
                int cb = ks * 64 + ((lane >> 4) * 16);
                dst[m][ks] = *(const bf16x8_t*)(base + ra * 128 + (cb ^ sw));
            }
        }
    };
    auto readB = [&](int tk) {
        const char* base = (const char*)&Bs[tk & 1][0];
        #pragma unroll
        for (int n = 0; n < 4; ++n) {
            int rb = wc * 64 + n * 16 + (lane & 15);
            int sw = (rb & 7) << 4;
            #pragma unroll
            for (int ks = 0; ks < 2; ++ks) {
                int cb = ks * 64 + ((lane >> 4) * 16);
                bfr[n][ks] = *(const bf16x8_t*)(base + rb * 128 + (cb ^ sw));
            }
        }
    };

#define QUAD66(AF, MH, NH)                                                          \
    do { __builtin_amdgcn_s_setprio(1);                                             \
        _Pragma("unroll") for (int m = 0; m < 4; ++m)                               \
        _Pragma("unroll") for (int n = 0; n < 2; ++n)                               \
        _Pragma("unroll") for (int ks = 0; ks < 2; ++ks)                            \
            acc[(MH) * 4 + m][(NH) * 2 + n] = __builtin_amdgcn_mfma_f32_16x16x32_bf16( \
                AF[m][ks], bfr[(NH) * 2 + n][ks], acc[(MH) * 4 + m][(NH) * 2 + n], 0, 0, 0); \
        __builtin_amdgcn_s_setprio(0); } while (0)

    // prologue: K0 fully + K1.A halves (12 loads)
    stageA(0, 0); stageA(0, 1); stageB(0, 0); stageB(0, 1);
    stageA(1, 0); stageA(1, 1);
    GATE(4);
    __builtin_amdgcn_s_barrier();

    for (int i = 0; i < niter; ++i) {
        int t2 = 2 * i, u = 2 * i + 1;
        bool smid = (t2 + 2 < nkt);   // false only in last iteration
        // P1: reads t2 (afl + B), stage u.B0
        readAhalf(t2, 0, afl); readB(t2);
        stageB(u, 0);
        PRE_BAR(); QUAD66(afl, 0, 0); POST_BAR();
        // P2: read afh(t2), stage u.B1
        readAhalf(t2, 1, afh);
        stageB(u, 1);
        PRE_BAR(); QUAD66(afl, 0, 1); POST_BAR();
        // P3: stage t2+2.A0
        if (smid) stageA(t2 + 2, 0);
        PRE_BAR(); QUAD66(afh, 1, 0); POST_BAR();
        // P4: stage t2+2.A1, gate for u reads
        if (smid) stageA(t2 + 2, 1);
        PRE_BAR(); QUAD66(afh, 1, 1);
        if (smid) { GATE(4); } else { GATE(0); }
        POST_BAR();
        // P5: reads u (afl + B), stage t2+2.B0
        readAhalf(u, 0, afl); readB(u);
        if (smid) stageB(t2 + 2, 0);
        PRE_BAR(); QUAD66(afl, 0, 0); POST_BAR();
        // P6: read afh(u), stage t2+2.B1
        readAhalf(u, 1, afh);
        if (smid) stageB(t2 + 2, 1);
        PRE_BAR(); QUAD66(afl, 0, 1); POST_BAR();
        // P7: stage u+2.A0
        if (smid) stageA(u + 2, 0);
        PRE_BAR(); QUAD66(afh, 1, 0); POST_BAR();
        // P8: stage u+2.A1, gate for next t2 reads
        if (smid) stageA(u + 2, 1);
        PRE_BAR(); QUAD66(afh, 1, 1);
        if (smid) { GATE(4); } else { GATE(0); }
        POST_BAR();
    }
#undef QUAD66

    int crow0 = brow + wr * 128 + ((lane >> 4) * 4);
    int ccol0 = bcol + wc * 64 + (lane & 15);
    #pragma unroll
    for (int mf = 0; mf < 8; ++mf) {
        #pragma unroll
        for (int nf = 0; nf < 4; ++nf) {
            int col = ccol0 + nf * 16;
            float bv = bias[col];
            #pragma unroll
            for (int j = 0; j < 4; ++j) {
                int rowg = crow0 + mf * 16 + j;
                Cout[(size_t)rowg * ldc + col] = f32_to_bf16(acc[mf][nf][j] + bv);
            }
        }
    }
}

// ---------------------------------------------------------------------
// 256x128 tile, BK=64, 512 thr (8 waves 4x2), wave tile 64x64. LOGITS/OUT.
// LDS: A 2x32KB + B 2x16KB = 96 KB.
// ---------------------------------------------------------------------
template<int MODE>
__global__ __launch_bounds__(512, 2)
void gemm_128_kernel(const ushort* __restrict__ A, const ushort* __restrict__ Bt,
                     float* __restrict__ Cout,
                     int K, int lda, int ldb, int ldc,
                     long strideA, long strideB, long strideC, float scale) {
    __shared__ ushort As[2][256 * 64];
    __shared__ ushort Bs[2][128 * 64];
    int bc, br;
    xcd_swizzle(bc, br);
    int bz = blockIdx.z;
    if (MODE == MODE_LOGITS && bc > 2 * br + 1) return;  // fully-masked causal block
    const ushort* Ab = A + (size_t)bz * strideA;
    const ushort* Bb = Bt + (size_t)bz * strideB;
    int brow = br * 256, bcol = bc * 128;
    int t = threadIdx.x, lane = t & 63, wid = t >> 6;
    int wr = wid >> 1, wc = wid & 1;
    int nkt = K / 64;
    if (MODE == MODE_OUT) nkt = min(nkt, (brow + 256) / 64);
    int niter = nkt >> 1;

    auto stageA = [&](int tk, int half) {
        ushort* dst = &As[tk & 1][0];
        #pragma unroll
        for (int j = 0; j < 2; ++j) {
            int o = half * 16384 + (j * 512 + t) * 16;
            int row = o >> 7;
            int col = (o & 127) ^ ((row & 7) << 4);
            const ushort* src = Ab + (size_t)(brow + row) * lda + tk * 64 + (col >> 1);
            __builtin_amdgcn_global_load_lds(
                (const __attribute__((address_space(1))) uint32_t*)src,
                (__attribute__((address_space(3))) uint32_t*)(dst + (o >> 1)), 16, 0, 0);
        }
    };
    auto stageB = [&](int tk) {
        ushort* dst = &Bs[tk & 1][0];
        #pragma unroll
        for (int j = 0; j < 2; ++j) {
            int o = (j * 512 + t) * 16;
            int row = o >> 7;
            int col = (o & 127) ^ ((row & 7) << 4);
            const ushort* src = Bb + (size_t)(bcol + row) * ldb + tk * 64 + (col >> 1);
            __builtin_amdgcn_global_load_lds(
                (const __attribute__((address_space(1))) uint32_t*)src,
                (__attribute__((address_space(3))) uint32_t*)(dst + (o >> 1)), 16, 0, 0);
        }
    };

    f32x4_t acc[4][4];
    #pragma unroll
    for (int m = 0; m < 4; ++m)
        #pragma unroll
        for (int n = 0; n < 4; ++n)
            acc[m][n] = (f32x4_t){0.f, 0.f, 0.f, 0.f};

    bf16x8_t af[4][2], bfr[4][2];

    auto readAll = [&](int tk) {
        const char* baseA = (const char*)&As[tk & 1][0];
        #pragma unroll
        for (int m = 0; m < 4; ++m) {
            int ra = wr * 64 + m * 16 + (lane & 15);
            int sw = (ra & 7) << 4;
            #pragma unroll
            for (int ks = 0; ks < 2; ++ks) {
                int cb = ks * 64 + ((lane >> 4) * 16);
                af[m][ks] = *(const bf16x8_t*)(baseA + ra * 128 + (cb ^ sw));
            }
        }
        const char* baseB = (const char*)&Bs[tk & 1][0];
        #pragma unroll
        for (int n = 0; n < 4; ++n) {
            int rb = wc * 64 + n * 16 + (lane & 15);
            int sw = (rb & 7) << 4;
            #pragma unroll
            for (int ks = 0; ks < 2; ++ks) {
                int cb = ks * 64 + ((lane >> 4) * 16);
                bfr[n][ks] = *(const bf16x8_t*)(baseB + rb * 128 + (cb ^ sw));
            }
        }
    };

#define QUAD28(MH, NH)                                                              \
    do { __builtin_amdgcn_s_setprio(1);                                             \
        _Pragma("unroll") for (int m = 0; m < 2; ++m)                               \
        _Pragma("unroll") for (int n = 0; n < 2; ++n)                               \
        _Pragma("unroll") for (int ks = 0; ks < 2; ++ks)                            \
            acc[(MH) * 2 + m][(NH) * 2 + n] = __builtin_amdgcn_mfma_f32_16x16x32_bf16( \
                af[(MH) * 2 + m][ks], bfr[(NH) * 2 + n][ks], acc[(MH) * 2 + m][(NH) * 2 + n], 0, 0, 0); \
        __builtin_amdgcn_s_setprio(0); } while (0)

    // prologue: K0 + K1 fully (12 loads)
    stageA(0, 0); stageA(0, 1); stageB(0);
    stageA(1, 0); stageA(1, 1); stageB(1);
    GATE(6);
    __builtin_amdgcn_s_barrier();

    for (int i = 0; i < niter; ++i) {
        int t2 = 2 * i, u = 2 * i + 1;
        bool smid = (t2 + 2 < nkt);   // false only in last iteration
        // P1: read all of t2
        readAll(t2);
        PRE_BAR(); QUAD28(0, 0); POST_BAR();
        // P2
        PRE_BAR(); QUAD28(0, 1); POST_BAR();
        // P3: stage t2+2.A0
        if (smid) stageA(t2 + 2, 0);
        PRE_BAR(); QUAD28(1, 0); POST_BAR();
        // P4: stage t2+2.A1, gate for u reads
        if (smid) stageA(t2 + 2, 1);
        PRE_BAR(); QUAD28(1, 1);
        if (smid) { GATE(4); } else { GATE(0); }
        POST_BAR();
        // P5: read all of u, stage t2+2.B
        readAll(u);
        if (smid) stageB(t2 + 2);
        PRE_BAR(); QUAD28(0, 0); POST_BAR();
        // P6: stage u+2.A0
        if (smid) stageA(u + 2, 0);
        PRE_BAR(); QUAD28(0, 1); POST_BAR();
        // P7: stage u+2.A1
        if (smid) stageA(u + 2, 1);
        PRE_BAR(); QUAD28(1, 0); POST_BAR();
        // P8: stage u+2.B, gate for next t2 reads
        if (smid) stageB(u + 2);
        PRE_BAR(); QUAD28(1, 1);
        if (smid) { GATE(6); } else { GATE(0); }
        POST_BAR();
    }
#undef QUAD28

    float* C = Cout + (size_t)bz * strideC;
    int crow0 = brow + wr * 64 + ((lane >> 4) * 4);
    int ccol0 = bcol + wc * 64 + (lane & 15);
    #pragma unroll
    for (int mf = 0; mf < 4; ++mf)
        #pragma unroll
        for (int nf = 0; nf < 4; ++nf) {
            int col = ccol0 + nf * 16;
            #pragma unroll
            for (int j = 0; j < 4; ++j) {
                int rowg = crow0 + mf * 16 + j;
                C[(size_t)rowg * ldc + col] = acc[mf][nf][j] * scale;
            }
        }
}

// ---------------- causal row softmax (in-place fp32, plus bf16 copy) ----------------
__global__ __launch_bounds__(256)
void softmax_causal_kernel(float* __restrict__ attn, ushort* __restrict__ attn_bf) {
    int rowid = blockIdx.x;
    int i = rowid & (S_LEN - 1);
    float* lrow = attn + (size_t)rowid * S_LEN;
    ushort* brw = attn_bf + (size_t)rowid * S_LEN;
    int t = threadIdx.x;
    int nvalid = i + 1;

    float vals[8];
    float lmax = -1e30f;
    #pragma unroll
    for (int it = 0; it < 8; ++it) {
        int j = it * 256 + t;
        float v = (j < nvalid) ? lrow[j] : -1e30f;
        vals[it] = v;
        lmax = fmaxf(lmax, v);
    }
    #pragma unroll
    for (int off = 32; off > 0; off >>= 1)
        lmax = fmaxf(lmax, __shfl_xor(lmax, off));

    __shared__ float redm[4];
    __shared__ float reds[4];
    int wave = t >> 6, lane = t & 63;
    if (lane == 0) redm[wave] = lmax;
    __syncthreads();
    float m = fmaxf(fmaxf(redm[0], redm[1]), fmaxf(redm[2], redm[3]));

    float lsum = 0.f;
    #pragma unroll
    for (int it = 0; it < 8; ++it) {
        int j = it * 256 + t;
        float e = (j < nvalid) ? __expf(vals[it] - m) : 0.f;
        vals[it] = e;
        lsum += e;
    }
    #pragma unroll
    for (int off = 32; off > 0; off >>= 1)
        lsum += __shfl_xor(lsum, off);
    if (lane == 0) reds[wave] = lsum;
    __syncthreads();
    float denom = reds[0] + reds[1] + reds[2] + reds[3];
    float inv = 1.f / denom;

    #pragma unroll
    for (int it = 0; it < 8; ++it) {
        int j = it * 256 + t;
        float p = vals[it] * inv;
        lrow[j] = p;
        brw[j] = f32_to_bf16(p);
    }
}

extern "C" void kernel_launch(void* const* d_in, const int* in_sizes, int n_in,
                              void* d_out, int out_size, void* d_ws, size_t ws_size,
                              hipStream_t stream) {
    const float* v  = (const float*)d_in[0];
    const float* k  = (const float*)d_in[1];
    const float* q  = (const float*)d_in[2];
    // d_in[3] = mask, unused (causality applied by index)
    const float* Wq = (const float*)d_in[4];
    const float* bq = (const float*)d_in[5];
    const float* Wk = (const float*)d_in[6];
    const float* bk = (const float*)d_in[7];
    const float* Wv = (const float*)d_in[8];
    const float* bv = (const float*)d_in[9];

    float* out  = (float*)d_out;                                        // [B,S,D]
    float* attn = (float*)d_out + (size_t)BATCH * S_LEN * D_DIM;        // [B,S,S]

    char* ws = (char*)d_ws;
    const size_t NTOK = (size_t)BATCH * S_LEN;                // 8192
    const size_t XSZ  = NTOK * D_DIM * sizeof(ushort);        // 16 MiB
    ushort* xqkv  = (ushort*)(ws);                            // [3][8192][1024] bf16
    ushort* qkvp  = (ushort*)(ws + 3 * XSZ);                  // [8192][3072] bf16
    ushort* WT    = (ushort*)(ws + 6 * XSZ);                  // [3072][1024] bf16
    float*  bias3 = (float*)(ws + 6 * XSZ + 3 * (size_t)D_DIM * D_DIM * sizeof(ushort));
    // aliases over xqkv (dead after projection GEMM):
    ushort* vpT     = (ushort*)(ws);            // [B][1024][2048] bf16
    ushort* attn_bf = (ushort*)(ws + XSZ);      // [B][2048][2048] bf16

    const int n4 = (int)(NTOK * D_DIM / 4);
    cvt3_kernel<<<dim3(1024, 3), dim3(256), 0, stream>>>(q, k, v, xqkv, n4);

    transpose_cvt_kernel<<<dim3(16, 16), dim3(256), 0, stream>>>(Wq, WT, D_DIM, D_DIM);
    transpose_cvt_kernel<<<dim3(16, 16), dim3(256), 0, stream>>>(Wk, WT + (size_t)D_DIM * D_DIM, D_DIM, D_DIM);
    transpose_cvt_kernel<<<dim3(16, 16), dim3(256), 0, stream>>>(Wv, WT + 2 * (size_t)D_DIM * D_DIM, D_DIM, D_DIM);
    bias_concat_kernel<<<dim3(12), dim3(256), 0, stream>>>(bq, bk, bv, bias3);

    // merged projections: M = 8192, N = 3072 (q|k|v), K = 1024
    gemm_proj_kernel<<<dim3(12, 32, 1), dim3(512), 0, stream>>>(
        xqkv, WT, bias3, qkvp, D_DIM, D_DIM, D_DIM, 3 * D_DIM, (long)NTOK * D_DIM);

    // vp (cols 2048..3071 of qkvp) -> vpT [B,D,S]
    transpose_bf16_kernel<<<dim3(D_DIM / 64, S_LEN / 64, BATCH), dim3(256), 0, stream>>>(
        qkvp + 2 * D_DIM, vpT, S_LEN, D_DIM, 3 * D_DIM,
        (long)S_LEN * 3 * D_DIM, (long)D_DIM * S_LEN);

    // logits = qp @ kp^T / 32, causal blocks only, fp32 into attn region of d_out
    gemm_128_kernel<MODE_LOGITS><<<dim3(16, 8, BATCH), dim3(512), 0, stream>>>(
        qkvp, qkvp + D_DIM, attn, D_DIM, 3 * D_DIM, 3 * D_DIM, S_LEN,
        (long)S_LEN * 3 * D_DIM, (long)S_LEN * 3 * D_DIM, (long)S_LEN * S_LEN, 0.03125f);

    // softmax rows (fp32 in-place in d_out; bf16 copy for PV)
    softmax_causal_kernel<<<dim3((int)NTOK), dim3(256), 0, stream>>>(attn, attn_bf);

    // out = attn_bf @ vp (via vpT), causal K-limit
    gemm_128_kernel<MODE_OUT><<<dim3(8, 8, BATCH), dim3(512), 0, stream>>>(
        attn_bf, vpT, out, S_LEN, S_LEN, S_LEN, D_DIM,
        (long)S_LEN * S_LEN, (long)D_DIM * S_LEN, (long)S_LEN * D_DIM, 1.f);
}

// Round 5
// 226.745 us; speedup vs baseline: 1.2448x; 1.0699x over previous
//
#include <hip/hip_runtime.h>
#include <hip/hip_bf16.h>
#include <cstdint>

#define BATCH 4
#define S_LEN 2048
#define D_DIM 1024

typedef __attribute__((ext_vector_type(4))) float f32x4_t;
typedef __attribute__((ext_vector_type(8))) __bf16 bf16x8_t;

__device__ __forceinline__ ushort f32_to_bf16(float f) {
    uint32_t u = __float_as_uint(f);
    uint32_t r = (u + 0x7FFFu + ((u >> 16) & 1u)) >> 16;
    return (ushort)r;
}

// ---------------- fp32 -> bf16 convert, 3 tensors in one launch ----------------
__global__ __launch_bounds__(256)
void cvt3_kernel(const float* __restrict__ a, const float* __restrict__ b,
                 const float* __restrict__ c, ushort* __restrict__ out, int n4) {
    int z = blockIdx.y;
    const float* src = (z == 0) ? a : ((z == 1) ? b : c);
    ushort* dst = out + (size_t)z * n4 * 4;
    int idx = blockIdx.x * blockDim.x + threadIdx.x;
    int stride = gridDim.x * blockDim.x;
    const float4* in4 = (const float4*)src;
    ushort4* out4 = (ushort4*)dst;
    for (int i = idx; i < n4; i += stride) {
        float4 v = in4[i];
        ushort4 o;
        o.x = f32_to_bf16(v.x);
        o.y = f32_to_bf16(v.y);
        o.z = f32_to_bf16(v.z);
        o.w = f32_to_bf16(v.w);
        out4[i] = o;
    }
}

// ---------------- fp32 [rows][cols] -> bf16 [cols][rows] ----------------
__global__ __launch_bounds__(256)
void transpose_cvt_kernel(const float* __restrict__ in, ushort* __restrict__ out,
                          int rows, int cols) {
    __shared__ ushort tile[64][66];
    int r0 = blockIdx.y * 64, c0 = blockIdx.x * 64;
    int t = threadIdx.x;
    int cr = t & 63;
    int cc = t >> 6;
    #pragma unroll
    for (int i = 0; i < 16; ++i) {
        int r = cc * 16 + i;
        tile[r][cr] = f32_to_bf16(in[(size_t)(r0 + r) * cols + (c0 + cr)]);
    }
    __syncthreads();
    #pragma unroll
    for (int i = 0; i < 16; ++i) {
        int c = cc * 16 + i;
        out[(size_t)(c0 + c) * rows + (r0 + cr)] = tile[cr][c];
    }
}

// ---------------- bf16 strided [rows][cols] -> bf16 [cols][rows], batched ----------------
__global__ __launch_bounds__(256)
void transpose_bf16_kernel(const ushort* __restrict__ in, ushort* __restrict__ out,
                           int rows, int cols, int lda, long strideA, long strideB) {
    __shared__ ushort tile[64][66];
    const ushort* src = in + (size_t)blockIdx.z * strideA;
    ushort* dst = out + (size_t)blockIdx.z * strideB;
    int r0 = blockIdx.y * 64, c0 = blockIdx.x * 64;
    int t = threadIdx.x;
    int cr = t & 63;
    int cc = t >> 6;
    #pragma unroll
    for (int i = 0; i < 16; ++i) {
        int r = cc * 16 + i;
        tile[r][cr] = src[(size_t)(r0 + r) * lda + (c0 + cr)];
    }
    __syncthreads();
    #pragma unroll
    for (int i = 0; i < 16; ++i) {
        int c = cc * 16 + i;
        dst[(size_t)(c0 + c) * rows + (r0 + cr)] = tile[cr][c];
    }
}

// ---------------- bias concat ----------------
__global__ __launch_bounds__(256)
void bias_concat_kernel(const float* __restrict__ bq, const float* __restrict__ bk,
                        const float* __restrict__ bv, float* __restrict__ out) {
    int i = blockIdx.x * blockDim.x + threadIdx.x;
    if (i < D_DIM) out[i] = bq[i];
    else if (i < 2 * D_DIM) out[i] = bk[i - D_DIM];
    else if (i < 3 * D_DIM) out[i] = bv[i - 2 * D_DIM];
}

// =====================================================================
// 8-phase GEMM schedules (T1+T2+T3+T4+T5), 4-6 phase gate flight.
// =====================================================================
enum { MODE_PROJ = 0, MODE_LOGITS = 1, MODE_OUT = 2 };

#define PRE_BAR() do { __builtin_amdgcn_s_barrier(); \
    asm volatile("s_waitcnt lgkmcnt(0)" ::: "memory"); \
    __builtin_amdgcn_sched_barrier(0); } while (0)
#define POST_BAR() do { __builtin_amdgcn_sched_barrier(0); \
    __builtin_amdgcn_s_barrier(); } while (0)
#define GATE(N) asm volatile("s_waitcnt vmcnt(" #N ")" ::: "memory")

#define GLOAD(dst, src) __builtin_amdgcn_global_load_lds( \
    (const __attribute__((address_space(1))) uint32_t*)(src), \
    (__attribute__((address_space(3))) uint32_t*)(dst), 16, 0, 0)

// bijective XCD swizzle over (x,y) grid, x fastest (requires nwg%8==0)
__device__ __forceinline__ void xcd_swizzle(int& bc, int& br) {
    int gx = gridDim.x;
    int nwg = gx * gridDim.y;
    int orig = blockIdx.y * gx + blockIdx.x;
    int xcd = orig & 7, idx = orig >> 3;
    int wgid = xcd * (nwg >> 3) + idx;
    bc = wgid % gx;
    br = wgid / gx;
}

// ---------------------------------------------------------------------
// PROJ: 256x256 tile, BK=64, 512 thr (8 waves 2x4), wave tile 128x64.
// LDS: A 2x32KB + B 2x32KB = 128 KB.
// ---------------------------------------------------------------------
__global__ __launch_bounds__(512, 2)
void gemm_proj_kernel(const ushort* __restrict__ A, const ushort* __restrict__ Bt,
                      const float* __restrict__ bias, ushort* __restrict__ Cout,
                      int K, int lda, int ldb, int ldc, long strideA) {
    __shared__ ushort As[2][256 * 64];
    __shared__ ushort Bs[2][256 * 64];
    int bc, br;
    xcd_swizzle(bc, br);
    const ushort* Ab = A + (size_t)(bc >> 2) * strideA;   // q/k/v select: 4 col-blocks each
    const ushort* Bb = Bt;
    int brow = br * 256, bcol = bc * 256;
    int t = threadIdx.x, lane = t & 63, wid = t >> 6;
    int wr = wid >> 2, wc = wid & 3;
    int nkt = K / 64, niter = nkt >> 1;

    auto stageA = [&](int tk) {   // 4 gload (32KB)
        ushort* dst = &As[tk & 1][0];
        #pragma unroll
        for (int j = 0; j < 4; ++j) {
            int o = (j * 512 + t) * 16;
            int row = o >> 7;
            int col = (o & 127) ^ ((row & 7) << 4);
            GLOAD(dst + (o >> 1), Ab + (size_t)(brow + row) * lda + tk * 64 + (col >> 1));
        }
    };
    auto stageB = [&](int tk) {   // 4 gload (32KB)
        ushort* dst = &Bs[tk & 1][0];
        #pragma unroll
        for (int j = 0; j < 4; ++j) {
            int o = (j * 512 + t) * 16;
            int row = o >> 7;
            int col = (o & 127) ^ ((row & 7) << 4);
            GLOAD(dst + (o >> 1), Bb + (size_t)(bcol + row) * ldb + tk * 64 + (col >> 1));
        }
    };

    f32x4_t acc[8][4];
    #pragma unroll
    for (int m = 0; m < 8; ++m)
        #pragma unroll
        for (int n = 0; n < 4; ++n)
            acc[m][n] = (f32x4_t){0.f, 0.f, 0.f, 0.f};

    bf16x8_t af[4][2], bfr[4][2];

    auto readA = [&](int tk, int mh) {     // 8 ds_read_b128
        const char* base = (const char*)&As[tk & 1][0];
        #pragma unroll
        for (int m = 0; m < 4; ++m) {
            int ra = wr * 128 + mh * 64 + m * 16 + (lane & 15);
            int sw = (ra & 7) << 4;
            #pragma unroll
            for (int ks = 0; ks < 2; ++ks) {
                int cb = ks * 64 + ((lane >> 4) * 16);
                af[m][ks] = *(const bf16x8_t*)(base + ra * 128 + (cb ^ sw));
            }
        }
    };
    auto readB = [&](int tk) {             // 8 ds_read_b128
        const char* base = (const char*)&Bs[tk & 1][0];
        #pragma unroll
        for (int n = 0; n < 4; ++n) {
            int rb = wc * 64 + n * 16 + (lane & 15);
            int sw = (rb & 7) << 4;
            #pragma unroll
            for (int ks = 0; ks < 2; ++ks) {
                int cb = ks * 64 + ((lane >> 4) * 16);
                bfr[n][ks] = *(const bf16x8_t*)(base + rb * 128 + (cb ^ sw));
            }
        }
    };

#define PQUAD(MH, NH)                                                               \
    do { __builtin_amdgcn_s_setprio(1);                                             \
        _Pragma("unroll") for (int m = 0; m < 4; ++m)                               \
        _Pragma("unroll") for (int n = 0; n < 2; ++n)                               \
        _Pragma("unroll") for (int ks = 0; ks < 2; ++ks)                            \
            acc[(MH) * 4 + m][(NH) * 2 + n] = __builtin_amdgcn_mfma_f32_16x16x32_bf16( \
                af[m][ks], bfr[(NH) * 2 + n][ks], acc[(MH) * 4 + m][(NH) * 2 + n], 0, 0, 0); \
        __builtin_amdgcn_s_setprio(0); } while (0)

    // prologue: tiles 0 and 1 (16 gload); gate tile0, leave tile1 in flight
    stageB(0); stageA(0); stageB(1); stageA(1);
    GATE(8);
    __builtin_amdgcn_s_barrier();

    for (int i = 0; i < niter; ++i) {
        int t2 = 2 * i, u = 2 * i + 1;
        bool smid = (t2 + 2 < nkt);
        // P1: read all of t2's A-half0 + B
        readA(t2, 0); readB(t2);
        PRE_BAR(); PQUAD(0, 0); POST_BAR();
        // P2: stage t2+2.B (B(t2) LDS-dead after P1)
        if (smid) stageB(t2 + 2);
        PRE_BAR(); PQUAD(0, 1); POST_BAR();
        // P3: read A-half1 of t2
        readA(t2, 1);
        PRE_BAR(); PQUAD(1, 0); POST_BAR();
        // P4: stage t2+2.A (A(t2) dead after P3); gate u's tile (staged P6/P8 prev iter)
        if (smid) stageA(t2 + 2);
        if (smid) { GATE(8); } else { GATE(0); }
        PRE_BAR(); PQUAD(1, 1); POST_BAR();
        // P5: read all of u's A-half0 + B
        readA(u, 0); readB(u);
        PRE_BAR(); PQUAD(0, 0); POST_BAR();
        // P6: stage u+2.B
        if (smid) stageB(u + 2);
        PRE_BAR(); PQUAD(0, 1); POST_BAR();
        // P7: read A-half1 of u
        readA(u, 1);
        PRE_BAR(); PQUAD(1, 0); POST_BAR();
        // P8: stage u+2.A; gate t2+2 (staged P2/P4, flight 4-6 phases)
        if (smid) stageA(u + 2);
        if (smid) { GATE(8); } else { GATE(0); }
        PRE_BAR(); PQUAD(1, 1); POST_BAR();
    }
#undef PQUAD

    int crow0 = brow + wr * 128 + ((lane >> 4) * 4);
    int ccol0 = bcol + wc * 64 + (lane & 15);
    #pragma unroll
    for (int mf = 0; mf < 8; ++mf) {
        #pragma unroll
        for (int nf = 0; nf < 4; ++nf) {
            int col = ccol0 + nf * 16;
            float bv = bias[col];
            #pragma unroll
            for (int j = 0; j < 4; ++j) {
                int rowg = crow0 + mf * 16 + j;
                Cout[(size_t)rowg * ldc + col] = f32_to_bf16(acc[mf][nf][j] + bv);
            }
        }
    }
}

// ---------------------------------------------------------------------
// LOGITS/OUT: 256x128 tile, BK=64, 512 thr (8 waves 4x2), wave tile 64x64.
// LDS: A 2x32KB + B 2x16KB = 96 KB.
// ---------------------------------------------------------------------
template<int MODE>
__global__ __launch_bounds__(512, 2)
void gemm_128_kernel(const ushort* __restrict__ A, const ushort* __restrict__ Bt,
                     float* __restrict__ Cout,
                     int K, int lda, int ldb, int ldc,
                     long strideA, long strideB, long strideC, float scale) {
    __shared__ ushort As[2][256 * 64];
    __shared__ ushort Bs[2][128 * 64];
    int bc, br;
    xcd_swizzle(bc, br);
    int bz = blockIdx.z;
    if (MODE == MODE_LOGITS && bc > 2 * br + 1) return;  // fully-masked causal block
    const ushort* Ab = A + (size_t)bz * strideA;
    const ushort* Bb = Bt + (size_t)bz * strideB;
    int brow = br * 256, bcol = bc * 128;
    int t = threadIdx.x, lane = t & 63, wid = t >> 6;
    int wr = wid >> 1, wc = wid & 1;
    int nkt = K / 64;
    if (MODE == MODE_OUT) nkt = min(nkt, (brow + 256) / 64);
    int niter = nkt >> 1;

    auto stageA = [&](int tk) {   // 4 gload (32KB)
        ushort* dst = &As[tk & 1][0];
        #pragma unroll
        for (int j = 0; j < 4; ++j) {
            int o = (j * 512 + t) * 16;
            int row = o >> 7;
            int col = (o & 127) ^ ((row & 7) << 4);
            GLOAD(dst + (o >> 1), Ab + (size_t)(brow + row) * lda + tk * 64 + (col >> 1));
        }
    };
    auto stageB = [&](int tk) {   // 2 gload (16KB)
        ushort* dst = &Bs[tk & 1][0];
        #pragma unroll
        for (int j = 0; j < 2; ++j) {
            int o = (j * 512 + t) * 16;
            int row = o >> 7;
            int col = (o & 127) ^ ((row & 7) << 4);
            GLOAD(dst + (o >> 1), Bb + (size_t)(bcol + row) * ldb + tk * 64 + (col >> 1));
        }
    };

    f32x4_t acc[4][4];
    #pragma unroll
    for (int m = 0; m < 4; ++m)
        #pragma unroll
        for (int n = 0; n < 4; ++n)
            acc[m][n] = (f32x4_t){0.f, 0.f, 0.f, 0.f};

    bf16x8_t af[2][2], bfr[4][2];

    auto readA = [&](int tk, int mh) {     // 4 ds_read_b128
        const char* base = (const char*)&As[tk & 1][0];
        #pragma unroll
        for (int m = 0; m < 2; ++m) {
            int ra = wr * 64 + mh * 32 + m * 16 + (lane & 15);
            int sw = (ra & 7) << 4;
            #pragma unroll
            for (int ks = 0; ks < 2; ++ks) {
                int cb = ks * 64 + ((lane >> 4) * 16);
                af[m][ks] = *(const bf16x8_t*)(base + ra * 128 + (cb ^ sw));
            }
        }
    };
    auto readB = [&](int tk) {             // 8 ds_read_b128
        const char* base = (const char*)&Bs[tk & 1][0];
        #pragma unroll
        for (int n = 0; n < 4; ++n) {
            int rb = wc * 64 + n * 16 + (lane & 15);
            int sw = (rb & 7) << 4;
            #pragma unroll
            for (int ks = 0; ks < 2; ++ks) {
                int cb = ks * 64 + ((lane >> 4) * 16);
                bfr[n][ks] = *(const bf16x8_t*)(base + rb * 128 + (cb ^ sw));
            }
        }
    };

#define PQUAD(MH, NH)                                                               \
    do { __builtin_amdgcn_s_setprio(1);                                             \
        _Pragma("unroll") for (int m = 0; m < 2; ++m)                               \
        _Pragma("unroll") for (int n = 0; n < 2; ++n)                               \
        _Pragma("unroll") for (int ks = 0; ks < 2; ++ks)                            \
            acc[(MH) * 2 + m][(NH) * 2 + n] = __builtin_amdgcn_mfma_f32_16x16x32_bf16( \
                af[m][ks], bfr[(NH) * 2 + n][ks], acc[(MH) * 2 + m][(NH) * 2 + n], 0, 0, 0); \
        __builtin_amdgcn_s_setprio(0); } while (0)

    // prologue: tiles 0 and 1 (12 gload); gate tile0, leave tile1 in flight
    stageB(0); stageA(0); stageB(1); stageA(1);
    GATE(6);
    __builtin_amdgcn_s_barrier();

    for (int i = 0; i < niter; ++i) {
        int t2 = 2 * i, u = 2 * i + 1;
        bool smid = (t2 + 2 < nkt);
        // P1
        readA(t2, 0); readB(t2);
        PRE_BAR(); PQUAD(0, 0); POST_BAR();
        // P2
        if (smid) stageB(t2 + 2);
        PRE_BAR(); PQUAD(0, 1); POST_BAR();
        // P3
        readA(t2, 1);
        PRE_BAR(); PQUAD(1, 0); POST_BAR();
        // P4
        if (smid) stageA(t2 + 2);
        if (smid) { GATE(6); } else { GATE(0); }
        PRE_BAR(); PQUAD(1, 1); POST_BAR();
        // P5
        readA(u, 0); readB(u);
        PRE_BAR(); PQUAD(0, 0); POST_BAR();
        // P6
        if (smid) stageB(u + 2);
        PRE_BAR(); PQUAD(0, 1); POST_BAR();
        // P7
        readA(u, 1);
        PRE_BAR(); PQUAD(1, 0); POST_BAR();
        // P8
        if (smid) stageA(u + 2);
        if (smid) { GATE(6); } else { GATE(0); }
        PRE_BAR(); PQUAD(1, 1); POST_BAR();
    }
#undef PQUAD

    float* C = Cout + (size_t)bz * strideC;
    int crow0 = brow + wr * 64 + ((lane >> 4) * 4);
    int ccol0 = bcol + wc * 64 + (lane & 15);
    #pragma unroll
    for (int mf = 0; mf < 4; ++mf)
        #pragma unroll
        for (int nf = 0; nf < 4; ++nf) {
            int col = ccol0 + nf * 16;
            #pragma unroll
            for (int j = 0; j < 4; ++j) {
                int rowg = crow0 + mf * 16 + j;
                C[(size_t)rowg * ldc + col] = acc[mf][nf][j] * scale;
            }
        }
}

// ---------------- causal row softmax (in-place fp32, plus bf16 copy) ----------------
__global__ __launch_bounds__(256)
void softmax_causal_kernel(float* __restrict__ attn, ushort* __restrict__ attn_bf) {
    int rowid = blockIdx.x;
    int i = rowid & (S_LEN - 1);
    float* lrow = attn + (size_t)rowid * S_LEN;
    ushort* brw = attn_bf + (size_t)rowid * S_LEN;
    int t = threadIdx.x;
    int nvalid = i + 1;

    float vals[8];
    float lmax = -1e30f;
    #pragma unroll
    for (int it = 0; it < 8; ++it) {
        int j = it * 256 + t;
        float v = (j < nvalid) ? lrow[j] : -1e30f;
        vals[it] = v;
        lmax = fmaxf(lmax, v);
    }
    #pragma unroll
    for (int off = 32; off > 0; off >>= 1)
        lmax = fmaxf(lmax, __shfl_xor(lmax, off));

    __shared__ float redm[4];
    __shared__ float reds[4];
    int wave = t >> 6, lane = t & 63;
    if (lane == 0) redm[wave] = lmax;
    __syncthreads();
    float m = fmaxf(fmaxf(redm[0], redm[1]), fmaxf(redm[2], redm[3]));

    float lsum = 0.f;
    #pragma unroll
    for (int it = 0; it < 8; ++it) {
        int j = it * 256 + t;
        float e = (j < nvalid) ? __expf(vals[it] - m) : 0.f;
        vals[it] = e;
        lsum += e;
    }
    #pragma unroll
    for (int off = 32; off > 0; off >>= 1)
        lsum += __shfl_xor(lsum, off);
    if (lane == 0) reds[wave] = lsum;
    __syncthreads();
    float denom = reds[0] + reds[1] + reds[2] + reds[3];
    float inv = 1.f / denom;

    #pragma unroll
    for (int it = 0; it < 8; ++it) {
        int j = it * 256 + t;
        float p = vals[it] * inv;
        lrow[j] = p;
        brw[j] = f32_to_bf16(p);
    }
}

extern "C" void kernel_launch(void* const* d_in, const int* in_sizes, int n_in,
                              void* d_out, int out_size, void* d_ws, size_t ws_size,
                              hipStream_t stream) {
    const float* v  = (const float*)d_in[0];
    const float* k  = (const float*)d_in[1];
    const float* q  = (const float*)d_in[2];
    // d_in[3] = mask, unused (causality applied by index)
    const float* Wq = (const float*)d_in[4];
    const float* bq = (const float*)d_in[5];
    const float* Wk = (const float*)d_in[6];
    const float* bk = (const float*)d_in[7];
    const float* Wv = (const float*)d_in[8];
    const float* bv = (const float*)d_in[9];

    float* out  = (float*)d_out;                                        // [B,S,D]
    float* attn = (float*)d_out + (size_t)BATCH * S_LEN * D_DIM;        // [B,S,S]

    char* ws = (char*)d_ws;
    const size_t NTOK = (size_t)BATCH * S_LEN;                // 8192
    const size_t XSZ  = NTOK * D_DIM * sizeof(ushort);        // 16 MiB
    ushort* xqkv  = (ushort*)(ws);                            // [3][8192][1024] bf16
    ushort* qkvp  = (ushort*)(ws + 3 * XSZ);                  // [8192][3072] bf16
    ushort* WT    = (ushort*)(ws + 6 * XSZ);                  // [3072][1024] bf16
    float*  bias3 = (float*)(ws + 6 * XSZ + 3 * (size_t)D_DIM * D_DIM * sizeof(ushort));
    // aliases over xqkv (dead after projection GEMM):
    ushort* vpT     = (ushort*)(ws);            // [B][1024][2048] bf16
    ushort* attn_bf = (ushort*)(ws + XSZ);      // [B][2048][2048] bf16

    const int n4 = (int)(NTOK * D_DIM / 4);
    cvt3_kernel<<<dim3(1024, 3), dim3(256), 0, stream>>>(q, k, v, xqkv, n4);

    transpose_cvt_kernel<<<dim3(16, 16), dim3(256), 0, stream>>>(Wq, WT, D_DIM, D_DIM);
    transpose_cvt_kernel<<<dim3(16, 16), dim3(256), 0, stream>>>(Wk, WT + (size_t)D_DIM * D_DIM, D_DIM, D_DIM);
    transpose_cvt_kernel<<<dim3(16, 16), dim3(256), 0, stream>>>(Wv, WT + 2 * (size_t)D_DIM * D_DIM, D_DIM, D_DIM);
    bias_concat_kernel<<<dim3(12), dim3(256), 0, stream>>>(bq, bk, bv, bias3);

    // merged projections: M = 8192, N = 3072 (q|k|v), K = 1024
    gemm_proj_kernel<<<dim3(12, 32, 1), dim3(512), 0, stream>>>(
        xqkv, WT, bias3, qkvp, D_DIM, D_DIM, D_DIM, 3 * D_DIM, (long)NTOK * D_DIM);

    // vp (cols 2048..3071 of qkvp) -> vpT [B,D,S]
    transpose_bf16_kernel<<<dim3(D_DIM / 64, S_LEN / 64, BATCH), dim3(256), 0, stream>>>(
        qkvp + 2 * D_DIM, vpT, S_LEN, D_DIM, 3 * D_DIM,
        (long)S_LEN * 3 * D_DIM, (long)D_DIM * S_LEN);

    // logits = qp @ kp^T / 32, causal blocks only, fp32 into attn region of d_out
    gemm_128_kernel<MODE_LOGITS><<<dim3(16, 8, BATCH), dim3(512), 0, stream>>>(
        qkvp, qkvp + D_DIM, attn, D_DIM, 3 * D_DIM, 3 * D_DIM, S_LEN,
        (long)S_LEN * 3 * D_DIM, (long)S_LEN * 3 * D_DIM, (long)S_LEN * S_LEN, 0.03125f);

    // softmax rows (fp32 in-place in d_out; bf16 copy for PV)
    softmax_causal_kernel<<<dim3((int)NTOK), dim3(256), 0, stream>>>(attn, attn_bf);

    // out = attn_bf @ vp (via vpT), causal K-limit
    gemm_128_kernel<MODE_OUT><<<dim3(8, 8, BATCH), dim3(512), 0, stream>>>(
        attn_bf, vpT, out, S_LEN, S_LEN, S_LEN, D_DIM,
        (long)S_LEN * S_LEN, (long)D_DIM * S_LEN, (long)S_LEN * D_DIM, 1.f);
}